// Round 4
// baseline (2565.074 us; speedup 1.0000x reference)
//
#include <hip/hip_runtime.h>
#include <hip/hip_bf16.h>
#include <math.h>

#define HIDN 256
#define GATES 1024
#define BB 8
#define LLEN 128
#define WLEN 48
#define SNUM 5
#define PLEN 32
#define NSEQ 1024
#define EMBD 256

typedef short short8_t __attribute__((ext_vector_type(8)));
typedef float f32x4 __attribute__((ext_vector_type(4)));

__device__ __forceinline__ float sigf(float x){ return 1.0f/(1.0f+expf(-x)); }

__device__ __forceinline__ unsigned short f2bf(float f){
  unsigned int x = __builtin_bit_cast(unsigned int, f);
  x += 0x7fffu + ((x >> 16) & 1u);
  return (unsigned short)(x >> 16);
}

// =======================================================================
// Generalized tiled GEMM: C(MxN) = op(A)(MxK) @ B(NxK)^T [+bias] [relu]
// =======================================================================
template<bool GATHER, bool BIAS, bool RELU, bool SPLIT>
__global__ __launch_bounds__(256) void gemm_abt64_k(
  const float* __restrict__ A, const float* __restrict__ A2,
  const float* __restrict__ Bm, const float* __restrict__ bias,
  float* __restrict__ C, const int* __restrict__ gidx,
  int K, int N, int ostride)
{
  __shared__ float As[32][68];
  __shared__ float Bs[32][68];
  const int tid = threadIdx.x;
  const int m0 = blockIdx.x*64, n0 = blockIdx.y*64;
  const int tx = tid & 15, ty = tid >> 4;
  const int lr = tid >> 3;
  const int lc = (tid & 7) * 4;
  float acc[4][4] = {};
  for (int k0 = 0; k0 < K; k0 += 32){
    #pragma unroll
    for (int hf = 0; hf < 2; ++hf){
      const int r = lr + hf*32;
      int am = m0 + r;
      if (GATHER) am = gidx[am];
      const float* asrc;
      if (SPLIT){
        if (k0 < 256) asrc = A  + (size_t)am*256 + k0 + lc;
        else          asrc = A2 + (size_t)am*256 + (k0-256) + lc;
      } else {
        asrc = A + (size_t)am*K + k0 + lc;
      }
      float4 av = *reinterpret_cast<const float4*>(asrc);
      float4 bv = *reinterpret_cast<const float4*>(Bm + (size_t)(n0+r)*K + k0 + lc);
      As[lc+0][r]=av.x; As[lc+1][r]=av.y; As[lc+2][r]=av.z; As[lc+3][r]=av.w;
      Bs[lc+0][r]=bv.x; Bs[lc+1][r]=bv.y; Bs[lc+2][r]=bv.z; Bs[lc+3][r]=bv.w;
    }
    __syncthreads();
    #pragma unroll
    for (int kk = 0; kk < 32; ++kk){
      const float4 a = *reinterpret_cast<const float4*>(&As[kk][ty*4]);
      const float4 b = *reinterpret_cast<const float4*>(&Bs[kk][tx*4]);
      acc[0][0] += a.x*b.x; acc[0][1] += a.x*b.y; acc[0][2] += a.x*b.z; acc[0][3] += a.x*b.w;
      acc[1][0] += a.y*b.x; acc[1][1] += a.y*b.y; acc[1][2] += a.y*b.z; acc[1][3] += a.y*b.w;
      acc[2][0] += a.z*b.x; acc[2][1] += a.z*b.y; acc[2][2] += a.z*b.z; acc[2][3] += a.z*b.w;
      acc[3][0] += a.w*b.x; acc[3][1] += a.w*b.y; acc[3][2] += a.w*b.z; acc[3][3] += a.w*b.w;
    }
    __syncthreads();
  }
  float4 bb;
  if (BIAS) bb = *reinterpret_cast<const float4*>(bias + n0 + tx*4);
  else      { bb.x=0.f; bb.y=0.f; bb.z=0.f; bb.w=0.f; }
  #pragma unroll
  for (int i = 0; i < 4; ++i){
    float4 o;
    o.x = acc[i][0]+bb.x; o.y = acc[i][1]+bb.y; o.z = acc[i][2]+bb.z; o.w = acc[i][3]+bb.w;
    if (RELU){ o.x=fmaxf(o.x,0.f); o.y=fmaxf(o.y,0.f); o.z=fmaxf(o.z,0.f); o.w=fmaxf(o.w,0.f); }
    *reinterpret_cast<float4*>(C + (size_t)(m0+ty*4+i)*ostride + n0 + tx*4) = o;
  }
}

// =======================================================================
// gather-index remap: gidx2[t*1024 + u] = tok[u*48 + t]
// =======================================================================
__global__ __launch_bounds__(256) void remap_k(const int* __restrict__ tok, int* __restrict__ gidx2){
  const int idx = blockIdx.x*256 + threadIdx.x;   // 0..49151
  const int t = idx >> 10, u = idx & 1023;
  gidx2[idx] = tok[u*WLEN + t];
}

// =======================================================================
// Persistent multi-block LSTM with LDS-resident bf16 weights + MFMA.
// Hidden dim split into 4 j-slices (one block each); each block owns
// 256 gate rows (4 quadrants x 64) = 128 KB bf16 LDS, staged once.
// Blocks of a sequence-group exchange 64-wide h slices through global
// (bf16, parity double-buffer) with device-scope release/acquire counters.
// mode 0: word LSTM, 256 blocks = 64 groups x 4 slices, T=48, X=[t][seq][g].
// mode 1: conv (blocks 0-3, T=128, 8 seqs) + sess (blocks 4-11, 2 groups
//         of 16 seqs, T=32), X=[seq][t][g].
// =======================================================================
__global__ __launch_bounds__(256, 1) void lstm_pers_k(
  int mode,
  const float* __restrict__ Xa, const float* __restrict__ Xb,
  const float* __restrict__ Wa, const float* __restrict__ Wb,
  float* __restrict__ outa, float* __restrict__ outb,
  unsigned short* __restrict__ hglob, int hrows,
  int* __restrict__ cnt)
{
  extern __shared__ char smem[];
  float* gl = (float*)(smem + 131072);   // [4*64][17] f32 gate exchange

  const int bid = blockIdx.x, tid = threadIdx.x;
  int js, T, nseq, xt, xs, sxb, hbase, ogbase;
  const float *W, *X; float* out; int* cs;
  if (mode == 0){
    const int gid = bid >> 2; js = bid & 3;
    W = Wa; X = Xa; out = outa;
    T = WLEN; nseq = 16; xt = 1024; xs = 1;
    sxb = gid*16; hbase = gid*16; ogbase = gid*16;
    cs = cnt + gid*(WLEN+1);
  } else if (bid < 4){
    js = bid; W = Wa; X = Xa; out = outa;
    T = 128; nseq = 8; xt = 1; xs = 128;
    sxb = 0; hbase = 0; ogbase = 0;
    cs = cnt;
  } else {
    const int k = (bid-4) >> 2; js = (bid-4) & 3;
    W = Wb; X = Xb; out = outb;
    T = 32; nseq = 16; xt = 1; xs = 32;
    sxb = k*16; hbase = 16 + k*16; ogbase = k*16;
    cs = cnt + 129 + k*33;
  }

  // ---- stage weight slice into LDS (fp32 -> bf16, XOR-swizzled rows) ----
  {
    const int grow = ((tid>>6)*256) + js*64 + (tid&63);   // global gate row
    const float* src = W + (size_t)grow*256;
    char* wb = smem + tid*512;
    const int sw = (tid & 7) << 4;
    for (int ch = 0; ch < 32; ++ch){
      float4 f0 = *reinterpret_cast<const float4*>(src + ch*8);
      float4 f1 = *reinterpret_cast<const float4*>(src + ch*8 + 4);
      union { short8_t s; unsigned short u[8]; } pk;
      pk.u[0]=f2bf(f0.x); pk.u[1]=f2bf(f0.y); pk.u[2]=f2bf(f0.z); pk.u[3]=f2bf(f0.w);
      pk.u[4]=f2bf(f1.x); pk.u[5]=f2bf(f1.y); pk.u[6]=f2bf(f1.z); pk.u[7]=f2bf(f1.w);
      *reinterpret_cast<short8_t*>(wb + ((ch*16) ^ sw)) = pk.s;
    }
  }
  float c_reg[4] = {0.f, 0.f, 0.f, 0.f};
  __syncthreads();

  const int w  = tid >> 6;        // wave = gate quadrant
  const int l  = tid & 63;
  const int lr = l & 15, lg = l >> 4;
  const int jj = tid & 63, sgrp = tid >> 6;

  for (int t = 0; t < T; ++t){
    if (t > 0){
      if (tid == 0){
        while (__hip_atomic_load(cs + t, __ATOMIC_ACQUIRE, __HIP_MEMORY_SCOPE_AGENT) < 4)
          __builtin_amdgcn_s_sleep(8);
      }
      __syncthreads();
    }
    // A fragments: h_t rows hbase..hbase+15, lane lr = seq, lg = k-group
    short8_t afr[8];
    if (t == 0){
      #pragma unroll
      for (int ks = 0; ks < 8; ++ks) afr[ks] = short8_t{0,0,0,0,0,0,0,0};
    } else {
      const unsigned short* hs = hglob + (size_t)(t&1)*hrows*256
                               + (size_t)(hbase+lr)*256 + lg*8;
      #pragma unroll
      for (int ks = 0; ks < 8; ++ks)
        afr[ks] = *reinterpret_cast<const short8_t*>(hs + ks*32);
    }
    // MFMA: quadrant w, 4 n-tiles of 16 cols, K=256
    f32x4 acc[4] = { f32x4{0,0,0,0}, f32x4{0,0,0,0}, f32x4{0,0,0,0}, f32x4{0,0,0,0} };
    #pragma unroll
    for (int ks = 0; ks < 8; ++ks){
      #pragma unroll
      for (int nt = 0; nt < 4; ++nt){
        const int wrow = w*64 + nt*16 + lr;
        short8_t bf = *reinterpret_cast<const short8_t*>(
            smem + wrow*512 + ((ks*64 + lg*16) ^ ((wrow & 7) << 4)));
        acc[nt] = __builtin_amdgcn_mfma_f32_16x16x32_bf16(afr[ks], bf, acc[nt], 0, 0, 0);
      }
    }
    // D layout: row(seq) = lg*4 + r, col = lr  ->  gl[(q*64+col)][seq]
    #pragma unroll
    for (int nt = 0; nt < 4; ++nt){
      #pragma unroll
      for (int r = 0; r < 4; ++r)
        gl[(w*64 + nt*16 + lr)*17 + lg*4 + r] = acc[nt][r];
    }
    __syncthreads();
    // ---- fused LSTM update: thread -> (jj, 4 seqs) ----
    unsigned short* hd = hglob + (size_t)((t+1)&1)*hrows*256;
    #pragma unroll
    for (int i = 0; i < 4; ++i){
      const int s = sgrp*4 + i;
      const int scl = (s < nseq) ? s : (nseq-1);
      const size_t xrow = (size_t)t*xt + (size_t)(sxb+scl)*xs;
      const float* xp = X + xrow*GATES + js*64 + jj;
      float gi = gl[(0*64+jj)*17 + s] + xp[0];
      float gf = gl[(1*64+jj)*17 + s] + xp[256];
      float gg = gl[(2*64+jj)*17 + s] + xp[512];
      float go = gl[(3*64+jj)*17 + s] + xp[768];
      float cc = sigf(gf)*c_reg[i] + sigf(gi)*tanhf(gg);
      c_reg[i] = cc;
      float hh = sigf(go)*tanhf(cc);
      if (s < nseq){
        hd[(size_t)(hbase+s)*256 + js*64 + jj] = f2bf(hh);
        out[((size_t)(ogbase+s)*T + t)*256 + js*64 + jj] = hh;
      }
    }
    __syncthreads();
    if (tid == 0 && (t+1) < T)
      __hip_atomic_fetch_add(cs + (t+1), 1, __ATOMIC_RELEASE, __HIP_MEMORY_SCOPE_AGENT);
  }
}

// =======================================================================
// Fallback word LSTM gates (K=512) + update, if workspace too small for X
// =======================================================================
__global__ __launch_bounds__(256) void word_gates_k(
    const int* __restrict__ tok, const float* __restrict__ emb,
    const float* __restrict__ Wih, const float* __restrict__ Whh,
    const float* __restrict__ bias, const float* __restrict__ hbuf,
    float* __restrict__ G, int t)
{
  __shared__ float As[32][68];
  __shared__ float Bs[32][68];
  const int tid = threadIdx.x;
  const int m0 = blockIdx.x*64, n0 = blockIdx.y*64;
  const int tx = tid & 15, ty = tid >> 4;
  const int lr = tid >> 3;
  const int lc = (tid & 7) * 4;
  float acc[4][4] = {};
  for (int kt = 0; kt < 16; ++kt){
    const int k0 = (kt & 7)*32;
    const bool xp = (kt < 8);
    #pragma unroll
    for (int hf = 0; hf < 2; ++hf){
      const int r = lr + hf*32;
      float4 av, bv;
      if (xp){
        const int token = tok[(m0+r)*WLEN + t];
        av = *reinterpret_cast<const float4*>(emb + (size_t)token*EMBD + k0 + lc);
      } else {
        av = *reinterpret_cast<const float4*>(hbuf + (size_t)(m0+r)*HIDN + k0 + lc);
      }
      const float* bptr = (xp ? Wih : Whh) + (size_t)(n0+r)*HIDN + k0 + lc;
      bv = *reinterpret_cast<const float4*>(bptr);
      As[lc+0][r]=av.x; As[lc+1][r]=av.y; As[lc+2][r]=av.z; As[lc+3][r]=av.w;
      Bs[lc+0][r]=bv.x; Bs[lc+1][r]=bv.y; Bs[lc+2][r]=bv.z; Bs[lc+3][r]=bv.w;
    }
    __syncthreads();
    #pragma unroll
    for (int kk = 0; kk < 32; ++kk){
      const float4 a = *reinterpret_cast<const float4*>(&As[kk][ty*4]);
      const float4 b = *reinterpret_cast<const float4*>(&Bs[kk][tx*4]);
      acc[0][0] += a.x*b.x; acc[0][1] += a.x*b.y; acc[0][2] += a.x*b.z; acc[0][3] += a.x*b.w;
      acc[1][0] += a.y*b.x; acc[1][1] += a.y*b.y; acc[1][2] += a.y*b.z; acc[1][3] += a.y*b.w;
      acc[2][0] += a.z*b.x; acc[2][1] += a.z*b.y; acc[2][2] += a.z*b.z; acc[2][3] += a.z*b.w;
      acc[3][0] += a.w*b.x; acc[3][1] += a.w*b.y; acc[3][2] += a.w*b.z; acc[3][3] += a.w*b.w;
    }
    __syncthreads();
  }
  const float4 bb = *reinterpret_cast<const float4*>(bias + n0 + tx*4);
  #pragma unroll
  for (int i = 0; i < 4; ++i){
    float4 o;
    o.x = acc[i][0]+bb.x; o.y = acc[i][1]+bb.y; o.z = acc[i][2]+bb.z; o.w = acc[i][3]+bb.w;
    *reinterpret_cast<float4*>(G + (size_t)(m0+ty*4+i)*GATES + n0 + tx*4) = o;
  }
}

__global__ __launch_bounds__(256) void word_update_k(
  const float* __restrict__ G, float* __restrict__ h, float* __restrict__ c,
  float* __restrict__ wout, int t)
{
  int idx = blockIdx.x*256 + threadIdx.x;
  int m = idx >> 8, j = idx & 255;
  const float* g = G + (size_t)m*GATES;
  float gi = g[j], gf = g[HIDN+j], gg = g[2*HIDN+j], go = g[3*HIDN+j];
  float cc = c[idx];
  cc = sigf(gf)*cc + sigf(gi)*tanhf(gg);
  float hh = sigf(go)*tanhf(cc);
  c[idx] = cc; h[idx] = hh;
  wout[(size_t)m*WLEN*HIDN + (size_t)t*HIDN + j] = hh;
}

// =======================================================================
// attention logits (fused tanh + ws2 contraction)
// =======================================================================
__global__ __launch_bounds__(256) void att_logits_k(
  const float* __restrict__ wout, const float* __restrict__ ws1,
  const float* __restrict__ ws2, float* __restrict__ logits)
{
  __shared__ float As[64][33];
  __shared__ float Bs[256][33];
  __shared__ float red[64][16];
  const int tid = threadIdx.x;
  const int m0 = blockIdx.x*64;
  const int tx = tid & 15, ty = tid >> 4;
  const int lr = tid >> 3;
  const int lc = (tid & 7) * 4;
  float acc[4][16] = {};
  for (int k0 = 0; k0 < 256; k0 += 32){
    #pragma unroll
    for (int hf = 0; hf < 2; ++hf){
      const int r = lr + hf*32;
      float4 av = *reinterpret_cast<const float4*>(wout + (size_t)(m0+r)*HIDN + k0 + lc);
      As[r][lc+0]=av.x; As[r][lc+1]=av.y; As[r][lc+2]=av.z; As[r][lc+3]=av.w;
    }
    #pragma unroll
    for (int h8 = 0; h8 < 8; ++h8){
      const int r = lr + h8*32;
      float4 bv = *reinterpret_cast<const float4*>(ws1 + (size_t)r*HIDN + k0 + lc);
      Bs[r][lc+0]=bv.x; Bs[r][lc+1]=bv.y; Bs[r][lc+2]=bv.z; Bs[r][lc+3]=bv.w;
    }
    __syncthreads();
    for (int kk = 0; kk < 32; ++kk){
      float a0 = As[ty*4+0][kk], a1 = As[ty*4+1][kk], a2 = As[ty*4+2][kk], a3 = As[ty*4+3][kk];
      #pragma unroll
      for (int u = 0; u < 16; ++u){
        float b = Bs[tx + 16*u][kk];
        acc[0][u] += a0*b; acc[1][u] += a1*b; acc[2][u] += a2*b; acc[3][u] += a3*b;
      }
    }
    __syncthreads();
  }
  float p0=0, p1=0, p2=0, p3=0;
  #pragma unroll
  for (int u = 0; u < 16; ++u){
    float w2 = ws2[tx + 16*u];
    p0 += w2*tanhf(acc[0][u]);
    p1 += w2*tanhf(acc[1][u]);
    p2 += w2*tanhf(acc[2][u]);
    p3 += w2*tanhf(acc[3][u]);
  }
  red[ty*4+0][tx] = p0; red[ty*4+1][tx] = p1; red[ty*4+2][tx] = p2; red[ty*4+3][tx] = p3;
  __syncthreads();
  if (tid < 64){
    float s = 0;
    #pragma unroll
    for (int q = 0; q < 16; ++q) s += red[tid][q];
    logits[m0 + tid] = s;
  }
}

__global__ __launch_bounds__(256) void att_softmax_k(
  const float* __restrict__ wout, const float* __restrict__ logits,
  const int* __restrict__ tok, float* __restrict__ att)
{
  __shared__ float e[WLEN];
  __shared__ float den_s;
  const int n = blockIdx.x, j = threadIdx.x;
  if (j < WLEN){
    float l = logits[n*WLEN + j];
    if (tok[n*WLEN + j] == 0) l -= 10000.0f;
    e[j] = l;
  }
  __syncthreads();
  if (j == 0){
    float mx = -1e30f;
    for (int w = 0; w < WLEN; ++w) mx = fmaxf(mx, e[w]);
    float den = 0.f;
    for (int w = 0; w < WLEN; ++w){ float ee = expf(e[w]-mx); e[w] = ee; den += ee; }
    den_s = den;
  }
  __syncthreads();
  const float inv = 1.0f/den_s;
  float a = 0.f;
  for (int w = 0; w < WLEN; ++w)
    a += e[w]*wout[((size_t)n*WLEN + w)*HIDN + j];
  att[(size_t)n*HIDN + j] = a*inv;
}

// =======================================================================
// Parallel state "scan" prep (carry reaches back exactly one step)
// =======================================================================
__global__ __launch_bounds__(256) void scan_prep_k(
  const float* __restrict__ sess_out, const float* __restrict__ conv_out,
  const int* __restrict__ stm, float* __restrict__ state, float* __restrict__ onec)
{
  const int bl = blockIdx.x;
  const int b = bl >> 7, l = bl & 127;
  const int j = threadIdx.x;
  float ones = 0.f;
  #pragma unroll
  for (int s = 1; s < SNUM; ++s){
    const int sv = stm[(size_t)bl*SNUM + s];
    float vg = 0.f;
    if (sv > 0){
      int p = sv - 1; if (p > PLEN-1) p = PLEN-1;
      vg = sess_out[((size_t)(b*4 + (s-1))*PLEN + p)*HIDN + j];
    }
    float v = vg;
    if (sv == -1){
      v = 0.f;
      if (l > 0){
        const int pv = stm[(size_t)(bl-1)*SNUM + s];
        if (pv > 0){
          int p2 = pv - 1; if (p2 > PLEN-1) p2 = PLEN-1;
          v = sess_out[((size_t)(b*4 + (s-1))*PLEN + p2)*HIDN + j];
        }
      }
    }
    if (sv != 0) ones += v;
    state[((size_t)bl*SNUM + s)*HIDN + j] = vg;
  }
  onec[(size_t)bl*(2*HIDN) + j] = ones * 0.25f;
  const int lp = (l == 0) ? 0 : (l-1);
  onec[(size_t)bl*(2*HIDN) + HIDN + j] = conv_out[((size_t)(b*LLEN + lp))*HIDN + j];
}

// =======================================================================
// final scores + log_softmax
// =======================================================================
__global__ __launch_bounds__(256) void scores_k(
  const float* __restrict__ state, const float* __restrict__ up, float* __restrict__ out)
{
  const int n = blockIdx.x, j = threadIdx.x;
  __shared__ float red[SNUM][4];
  const float u = up[(size_t)n*HIDN + j];
  const int lane = j & 63, wid = j >> 6;
  #pragma unroll
  for (int s = 0; s < SNUM; ++s){
    float p = state[((size_t)n*SNUM + s)*HIDN + j]*u;
    for (int off = 32; off; off >>= 1) p += __shfl_down(p, off, 64);
    if (lane == 0) red[s][wid] = p;
  }
  __syncthreads();
  if (j == 0){
    float sc[SNUM]; float mx = -1e30f;
    #pragma unroll
    for (int s = 0; s < SNUM; ++s){
      sc[s] = red[s][0]+red[s][1]+red[s][2]+red[s][3];
      mx = fmaxf(mx, sc[s]);
    }
    float den = 0.f;
    #pragma unroll
    for (int s = 0; s < SNUM; ++s) den += expf(sc[s]-mx);
    const float ls = logf(den);
    #pragma unroll
    for (int s = 0; s < SNUM; ++s) out[(size_t)n*SNUM + s] = sc[s]-mx-ls;
  }
}

// ---------------- workspace layout (float offsets) ----------------
static const size_t OFF_WOUT  = 0;                        // 49152*256
static const size_t OFF_G     = 12582912;                 // 1024*1024 (fallback)
static const size_t OFF_H     = OFF_G     + 1048576;      // fallback h
static const size_t OFF_C     = OFF_H     + 262144;       // fallback c
static const size_t OFF_ATT   = OFF_C     + 262144;
static const size_t OFF_XWC   = OFF_ATT   + 262144;       // 1024*1024
static const size_t OFF_XWS   = OFF_XWC   + 1048576;
static const size_t OFF_CONV  = OFF_XWS   + 1048576;
static const size_t OFF_SOUT  = OFF_CONV  + 262144;
static const size_t OFF_STATE = OFF_SOUT  + 262144;       // 1024*5*256
static const size_t OFF_ONEC  = OFF_STATE + 1310720;      // 1024*512
static const size_t OFF_UP    = OFF_ONEC  + 524288;
static const size_t OFF_LOG   = OFF_UP    + 262144;       // 49152
static const size_t OFF_GIDX2 = OFF_LOG   + 49152;        // 49152 ints
static const size_t OFF_HGW   = OFF_GIDX2 + 49152;        // 2*1024*256 bf16 = 262144 f
static const size_t OFF_HG2   = OFF_HGW   + 262144;       // 2*48*256 bf16 = 12288 f
static const size_t OFF_CNT   = OFF_HG2   + 12288;        // 4096 ints
static const size_t OFF_X     = OFF_CNT   + 4096;         // 49152*1024 (optional)
static const size_t NEED_X_FLOATS = OFF_X + (size_t)49152*1024;

static const size_t LSTM_LDS_BYTES = 131072 + 4*64*17*4;  // 148480

extern "C" void kernel_launch(void* const* d_in, const int* in_sizes, int n_in,
                              void* d_out, int out_size, void* d_ws, size_t ws_size,
                              hipStream_t stream)
{
  const int*   tok   = (const int*)  d_in[0];
  const int*   perm  = (const int*)  d_in[2];
  const int*   stm   = (const int*)  d_in[3];
  const float* emb   = (const float*)d_in[5];
  const float* uWih  = (const float*)d_in[6];
  const float* uWhh  = (const float*)d_in[7];
  const float* ub    = (const float*)d_in[8];
  const float* ws1   = (const float*)d_in[9];
  const float* ws2   = (const float*)d_in[10];
  const float* cWih  = (const float*)d_in[11];
  const float* cWhh  = (const float*)d_in[12];
  const float* cb    = (const float*)d_in[13];
  const float* sWih  = (const float*)d_in[14];
  const float* sWhh  = (const float*)d_in[15];
  const float* sb    = (const float*)d_in[16];
  const float* Wp    = (const float*)d_in[17];
  const float* bp    = (const float*)d_in[18];
  const float* Ws    = (const float*)d_in[19];
  const float* bs    = (const float*)d_in[20];

  float* wsf    = (float*)d_ws;
  float* wout   = wsf + OFF_WOUT;
  float* G      = wsf + OFF_G;
  float* h      = wsf + OFF_H;
  float* c      = wsf + OFF_C;
  float* att    = wsf + OFF_ATT;
  float* xwc    = wsf + OFF_XWC;
  float* xws    = wsf + OFF_XWS;
  float* convb  = wsf + OFF_CONV;
  float* soutb  = wsf + OFF_SOUT;
  float* statem = wsf + OFF_STATE;
  float* onec   = wsf + OFF_ONEC;
  float* upb    = wsf + OFF_UP;
  float* logits = wsf + OFF_LOG;
  int*   gidx2  = (int*)(wsf + OFF_GIDX2);
  unsigned short* hgw = (unsigned short*)(wsf + OFF_HGW);
  unsigned short* hg2 = (unsigned short*)(wsf + OFF_HG2);
  int*   cnt    = (int*)(wsf + OFF_CNT);
  float* X      = wsf + OFF_X;

  const bool useX = ws_size >= NEED_X_FLOATS*sizeof(float);

  hipFuncSetAttribute(reinterpret_cast<const void*>(lstm_pers_k),
                      hipFuncAttributeMaxDynamicSharedMemorySize,
                      (int)LSTM_LDS_BYTES);

  // reset sync counters (word: 64*49 ints at 0; conv/sess at +3200)
  hipMemsetAsync(cnt, 0, 4096*sizeof(int), stream);

  // ---- word LSTM ----
  if (useX){
    // X[t][seq][gates] = emb[tok[seq][t]] @ Wih^T + b  (one big GEMM)
    remap_k<<<192, 256, 0, stream>>>(tok, gidx2);
    gemm_abt64_k<true,true,false,false><<<dim3(768,16), 256, 0, stream>>>(
      emb, nullptr, uWih, ub, X, gidx2, 256, GATES, GATES);
    lstm_pers_k<<<256, 256, LSTM_LDS_BYTES, stream>>>(
      0, X, nullptr, uWhh, nullptr, wout, nullptr, hgw, 1024, cnt);
  } else {
    hipMemsetAsync(h, 0, 2*262144*sizeof(float), stream);
    for (int t = 0; t < WLEN; ++t){
      word_gates_k<<<dim3(16,16), 256, 0, stream>>>(tok, emb, uWih, uWhh, ub, h, G, t);
      word_update_k<<<1024, 256, 0, stream>>>(G, h, c, wout, t);
    }
  }

  // ---- attention ----
  att_logits_k<<<768, 256, 0, stream>>>(wout, ws1, ws2, logits);
  att_softmax_k<<<1024, 256, 0, stream>>>(wout, logits, tok, att);

  // ---- x-parts of conv/session LSTMs (bias folded) ----
  gemm_abt64_k<false,true,false,false><<<dim3(16,16), 256, 0, stream>>>(
    att, nullptr, cWih, cb, xwc, nullptr, 256, GATES, GATES);
  gemm_abt64_k<true,true,false,false><<<dim3(16,16), 256, 0, stream>>>(
    att, nullptr, sWih, sb, xws, perm, 256, GATES, GATES);

  // ---- conv + sess recurrent LSTMs (LDS-resident bf16 weights, MFMA) ----
  lstm_pers_k<<<12, 256, LSTM_LDS_BYTES, stream>>>(
    1, xwc, xws, cWhh, sWhh, convb, soutb, hg2, 48, cnt + 3200);

  // ---- parallel state "scan" ----
  scan_prep_k<<<1024, 256, 0, stream>>>(soutb, convb, stm, statem, onec);
  gemm_abt64_k<false,true,true,false><<<dim3(16,4), 256, 0, stream>>>(
    onec, nullptr, Wp, bp, statem, nullptr, 512, HIDN, SNUM*HIDN);

  // ---- final projection + scores + log_softmax ----
  gemm_abt64_k<false,true,true,true><<<dim3(16,4), 256, 0, stream>>>(
    att, convb, Ws, bs, upb, nullptr, 512, HIDN, HIDN);
  scores_k<<<1024, 256, 0, stream>>>(statem, upb, (float*)d_out);
}

// Round 5
// 1256.677 us; speedup vs baseline: 2.0412x; 2.0412x over previous
//
#include <hip/hip_runtime.h>
#include <hip/hip_bf16.h>
#include <math.h>

#define HIDN 256
#define GATES 1024
#define BB 8
#define LLEN 128
#define WLEN 48
#define SNUM 5
#define PLEN 32
#define NSEQ 1024
#define EMBD 256

typedef _Float16 f16;
typedef _Float16 h2_t __attribute__((ext_vector_type(2)));
typedef short short8_t __attribute__((ext_vector_type(8)));
typedef float f32x4 __attribute__((ext_vector_type(4)));

__device__ __forceinline__ float sigf(float x){ return 1.0f/(1.0f+expf(-x)); }

__device__ __forceinline__ unsigned short f2bf(float f){
  unsigned int x = __builtin_bit_cast(unsigned int, f);
  x += 0x7fffu + ((x >> 16) & 1u);
  return (unsigned short)(x >> 16);
}
__device__ __forceinline__ float bf2f(unsigned short u){
  unsigned int x = ((unsigned int)u) << 16;
  return __builtin_bit_cast(float, x);
}

__device__ __forceinline__ float fd2(unsigned int w, unsigned int h, float acc){
  h2_t wa = __builtin_bit_cast(h2_t, w);
  h2_t hb = __builtin_bit_cast(h2_t, h);
#if defined(__has_builtin)
#if __has_builtin(__builtin_amdgcn_fdot2)
  return __builtin_amdgcn_fdot2(wa, hb, acc, false);
#else
  return acc + (float)wa[0]*(float)hb[0] + (float)wa[1]*(float)hb[1];
#endif
#else
  return acc + (float)wa[0]*(float)hb[0] + (float)wa[1]*(float)hb[1];
#endif
}

__device__ __forceinline__ float dot8(uint4 w, uint4 h, float acc){
  acc = fd2(w.x, h.x, acc);
  acc = fd2(w.y, h.y, acc);
  acc = fd2(w.z, h.z, acc);
  acc = fd2(w.w, h.w, acc);
  return acc;
}

// =======================================================================
// Generalized fp32 tiled GEMM: C(MxN) = op(A)(MxK) @ B(NxK)^T [+bias][relu]
// =======================================================================
template<bool GATHER, bool BIAS, bool RELU, bool SPLIT>
__global__ __launch_bounds__(256) void gemm_abt64_k(
  const float* __restrict__ A, const float* __restrict__ A2,
  const float* __restrict__ Bm, const float* __restrict__ bias,
  float* __restrict__ C, const int* __restrict__ gidx,
  int K, int N, int ostride)
{
  __shared__ float As[32][68];
  __shared__ float Bs[32][68];
  const int tid = threadIdx.x;
  const int m0 = blockIdx.x*64, n0 = blockIdx.y*64;
  const int tx = tid & 15, ty = tid >> 4;
  const int lr = tid >> 3;
  const int lc = (tid & 7) * 4;
  float acc[4][4] = {};
  for (int k0 = 0; k0 < K; k0 += 32){
    #pragma unroll
    for (int hf = 0; hf < 2; ++hf){
      const int r = lr + hf*32;
      int am = m0 + r;
      if (GATHER) am = gidx[am];
      const float* asrc;
      if (SPLIT){
        if (k0 < 256) asrc = A  + (size_t)am*256 + k0 + lc;
        else          asrc = A2 + (size_t)am*256 + (k0-256) + lc;
      } else {
        asrc = A + (size_t)am*K + k0 + lc;
      }
      float4 av = *reinterpret_cast<const float4*>(asrc);
      float4 bv = *reinterpret_cast<const float4*>(Bm + (size_t)(n0+r)*K + k0 + lc);
      As[lc+0][r]=av.x; As[lc+1][r]=av.y; As[lc+2][r]=av.z; As[lc+3][r]=av.w;
      Bs[lc+0][r]=bv.x; Bs[lc+1][r]=bv.y; Bs[lc+2][r]=bv.z; Bs[lc+3][r]=bv.w;
    }
    __syncthreads();
    #pragma unroll
    for (int kk = 0; kk < 32; ++kk){
      const float4 a = *reinterpret_cast<const float4*>(&As[kk][ty*4]);
      const float4 b = *reinterpret_cast<const float4*>(&Bs[kk][tx*4]);
      acc[0][0] += a.x*b.x; acc[0][1] += a.x*b.y; acc[0][2] += a.x*b.z; acc[0][3] += a.x*b.w;
      acc[1][0] += a.y*b.x; acc[1][1] += a.y*b.y; acc[1][2] += a.y*b.z; acc[1][3] += a.y*b.w;
      acc[2][0] += a.z*b.x; acc[2][1] += a.z*b.y; acc[2][2] += a.z*b.z; acc[2][3] += a.z*b.w;
      acc[3][0] += a.w*b.x; acc[3][1] += a.w*b.y; acc[3][2] += a.w*b.z; acc[3][3] += a.w*b.w;
    }
    __syncthreads();
  }
  float4 bb;
  if (BIAS) bb = *reinterpret_cast<const float4*>(bias + n0 + tx*4);
  else      { bb.x=0.f; bb.y=0.f; bb.z=0.f; bb.w=0.f; }
  #pragma unroll
  for (int i = 0; i < 4; ++i){
    float4 o;
    o.x = acc[i][0]+bb.x; o.y = acc[i][1]+bb.y; o.z = acc[i][2]+bb.z; o.w = acc[i][3]+bb.w;
    if (RELU){ o.x=fmaxf(o.x,0.f); o.y=fmaxf(o.y,0.f); o.z=fmaxf(o.z,0.f); o.w=fmaxf(o.w,0.f); }
    *reinterpret_cast<float4*>(C + (size_t)(m0+ty*4+i)*ostride + n0 + tx*4) = o;
  }
}

__global__ __launch_bounds__(256) void cvt_w16_k(
  const float* __restrict__ a, const float* __restrict__ b,
  f16* __restrict__ oa, f16* __restrict__ ob)
{
  const int i = blockIdx.x*256 + threadIdx.x;
  oa[i] = (f16)a[i];
  ob[i] = (f16)b[i];
}

__global__ __launch_bounds__(256) void cvt_bf16_k(
  const float* __restrict__ a, unsigned short* __restrict__ o, int n)
{
  for (int i = blockIdx.x*256 + threadIdx.x; i < n; i += gridDim.x*256)
    o[i] = f2bf(a[i]);
}

__global__ __launch_bounds__(256) void remap_k(const int* __restrict__ tok, int* __restrict__ gidx2){
  const int idx = blockIdx.x*256 + threadIdx.x;
  const int t = idx >> 10, u = idx & 1023;
  gidx2[idx] = tok[u*WLEN + t];
}

// =======================================================================
// X = emb[gidx] @ Wih^T + b  (bf16 MFMA, K=256 one-shot, 64x64 tile)
// =======================================================================
__global__ __launch_bounds__(256) void xgemm_k(
  const float* __restrict__ emb, const unsigned short* __restrict__ Wb,
  const float* __restrict__ bias, const int* __restrict__ gidx,
  float* __restrict__ X)
{
  __shared__ char As[32768];
  const int tid = threadIdx.x;
  const int w = tid >> 6, l = tid & 63;
  const int lr = l & 15, lg = l >> 4;
  const int m0 = blockIdx.x*64, n0 = blockIdx.y*64;
  #pragma unroll
  for (int rr = 0; rr < 4; ++rr){
    const int rl = rr*16 + (tid >> 4);
    const int c4 = tid & 15;
    const float* src = emb + (size_t)gidx[m0 + rl]*256;
    const int sw = (rl & 7) << 4;
    #pragma unroll
    for (int q = 0; q < 4; ++q){
      const int idx4 = c4 + q*16;
      float4 v = reinterpret_cast<const float4*>(src)[idx4];
      union { unsigned long long u; unsigned short us[4]; } pk;
      pk.us[0]=f2bf(v.x); pk.us[1]=f2bf(v.y); pk.us[2]=f2bf(v.z); pk.us[3]=f2bf(v.w);
      *reinterpret_cast<unsigned long long*>(As + rl*512 + ((idx4*8) ^ sw)) = pk.u;
    }
  }
  __syncthreads();
  short8_t a[8];
  #pragma unroll
  for (int ks = 0; ks < 8; ++ks){
    const int rl = w*16 + lr;
    a[ks] = *reinterpret_cast<const short8_t*>(As + rl*512 + ((ks*64 + lg*16) ^ ((rl&7)<<4)));
  }
  #pragma unroll
  for (int nt = 0; nt < 4; ++nt){
    f32x4 acc = f32x4{0,0,0,0};
    const int n = n0 + nt*16 + lr;
    #pragma unroll
    for (int ks = 0; ks < 8; ++ks){
      short8_t b = *reinterpret_cast<const short8_t*>(Wb + (size_t)n*256 + ks*32 + lg*8);
      acc = __builtin_amdgcn_mfma_f32_16x16x32_bf16(a[ks], b, acc, 0, 0, 0);
    }
    const float bn = bias[n];
    #pragma unroll
    for (int r = 0; r < 4; ++r){
      const int m = m0 + w*16 + lg*4 + r;
      X[(size_t)m*1024 + n] = acc[r] + bn;
    }
  }
}

// =======================================================================
// Word LSTM, seq-split: 64 blocks x 16 seqs, zero cross-block sync.
// =======================================================================
__global__ __launch_bounds__(256, 1) void word_stream_k(
  const float* __restrict__ X, const unsigned short* __restrict__ Wb,
  unsigned short* __restrict__ woutb)
{
  extern __shared__ char smem[];
  const int tid = threadIdx.x;
  const int w = tid >> 6, l = tid & 63;
  const int lr = l & 15, lg = l >> 4;
  const int S0 = blockIdx.x * 16;
  char* wlds = smem + w*32768;
  char* hb0 = smem + 131072;
  char* hb1 = smem + 139264;

  #pragma unroll
  for (int rr = 0; rr < 16; ++rr){
    const int rl = rr*4 + lg;
    const unsigned short* src = Wb + (size_t)(768 + w*64 + rl)*256;
    const int sw = (rl & 7) << 4;
    short8_t v0 = *reinterpret_cast<const short8_t*>(src + lr*8);
    short8_t v1 = *reinterpret_cast<const short8_t*>(src + (lr+16)*8);
    *reinterpret_cast<short8_t*>(wlds + rl*512 + ((lr*16) ^ sw)) = v0;
    *reinterpret_cast<short8_t*>(wlds + rl*512 + (((lr+16)*16) ^ sw)) = v1;
  }
  short8_t wr[96];
  #pragma unroll
  for (int g = 0; g < 3; ++g){
    #pragma unroll
    for (int jt = 0; jt < 4; ++jt){
      #pragma unroll
      for (int ks = 0; ks < 8; ++ks){
        const int n = g*256 + w*64 + jt*16 + lr;
        wr[(g*4 + jt)*8 + ks] = *reinterpret_cast<const short8_t*>(
            Wb + (size_t)n*256 + ks*32 + lg*8);
      }
    }
  }
  float c_reg[4][4] = {};
  __syncthreads();

  for (int t = 0; t < WLEN; ++t){
    const char* hr = (t & 1) ? hb1 : hb0;
    char* hw = (t & 1) ? hb0 : hb1;
    #pragma unroll
    for (int jt = 0; jt < 4; ++jt){
      f32x4 acc0 = f32x4{0,0,0,0}, acc1 = f32x4{0,0,0,0};
      f32x4 acc2 = f32x4{0,0,0,0}, acc3 = f32x4{0,0,0,0};
      #pragma unroll
      for (int ks = 0; ks < 8; ++ks){
        short8_t a;
        if (t == 0){
          a = short8_t{0,0,0,0,0,0,0,0};
        } else {
          const int kb = ks*64 + lg*16;
          a = *reinterpret_cast<const short8_t*>(hr + lr*512 + (kb ^ ((lr & 7) << 4)));
        }
        acc0 = __builtin_amdgcn_mfma_f32_16x16x32_bf16(a, wr[(0*4+jt)*8+ks], acc0, 0, 0, 0);
        acc1 = __builtin_amdgcn_mfma_f32_16x16x32_bf16(a, wr[(1*4+jt)*8+ks], acc1, 0, 0, 0);
        acc2 = __builtin_amdgcn_mfma_f32_16x16x32_bf16(a, wr[(2*4+jt)*8+ks], acc2, 0, 0, 0);
        const int rl_o = jt*16 + lr;
        short8_t bo = *reinterpret_cast<const short8_t*>(
            wlds + rl_o*512 + ((ks*64 + lg*16) ^ ((rl_o & 7) << 4)));
        acc3 = __builtin_amdgcn_mfma_f32_16x16x32_bf16(a, bo, acc3, 0, 0, 0);
      }
      const int j = w*64 + jt*16 + lr;
      #pragma unroll
      for (int r = 0; r < 4; ++r){
        const int s = lg*4 + r;
        const float* xp = X + ((size_t)t*1024 + (S0+s))*1024 + j;
        float gi = acc0[r] + xp[0];
        float gf = acc1[r] + xp[256];
        float gg = acc2[r] + xp[512];
        float go = acc3[r] + xp[768];
        float cc = sigf(gf)*c_reg[jt][r] + sigf(gi)*tanhf(gg);
        c_reg[jt][r] = cc;
        float hh = sigf(go)*tanhf(cc);
        unsigned short hb16 = f2bf(hh);
        woutb[((size_t)(S0+s)*WLEN + t)*256 + j] = hb16;
        *reinterpret_cast<unsigned short*>(hw + s*512 + ((j*2) ^ ((s & 7) << 4))) = hb16;
      }
    }
    __syncthreads();
  }
}

// =======================================================================
// attention logits via bf16 MFMA + fused tanh/ws2 contraction
// =======================================================================
__global__ __launch_bounds__(256) void attlog_k(
  const unsigned short* __restrict__ woutb, const unsigned short* __restrict__ ws1b,
  const float* __restrict__ ws2, float* __restrict__ logits)
{
  const int tid = threadIdx.x;
  const int w = tid >> 6, l = tid & 63;
  const int lr = l & 15, lg = l >> 4;
  const int m0 = blockIdx.x*64;
  short8_t a[8];
  #pragma unroll
  for (int ks = 0; ks < 8; ++ks){
    const int m = m0 + w*16 + lr;
    a[ks] = *reinterpret_cast<const short8_t*>(woutb + (size_t)m*256 + ks*32 + lg*8);
  }
  float part[4] = {0.f, 0.f, 0.f, 0.f};
  #pragma unroll
  for (int nt = 0; nt < 16; ++nt){
    f32x4 acc = f32x4{0,0,0,0};
    const int n = nt*16 + lr;
    #pragma unroll
    for (int ks = 0; ks < 8; ++ks){
      short8_t b = *reinterpret_cast<const short8_t*>(ws1b + (size_t)n*256 + ks*32 + lg*8);
      acc = __builtin_amdgcn_mfma_f32_16x16x32_bf16(a[ks], b, acc, 0, 0, 0);
    }
    const float w2 = ws2[n];
    #pragma unroll
    for (int r = 0; r < 4; ++r) part[r] += w2 * tanhf(acc[r]);
  }
  #pragma unroll
  for (int r = 0; r < 4; ++r){
    float p = part[r];
    p += __shfl_xor(p, 1, 64);
    p += __shfl_xor(p, 2, 64);
    p += __shfl_xor(p, 4, 64);
    p += __shfl_xor(p, 8, 64);
    if (lr == 0) logits[m0 + w*16 + lg*4 + r] = p;
  }
}

__global__ __launch_bounds__(256) void att_softmax_k(
  const unsigned short* __restrict__ woutb, const float* __restrict__ logits,
  const int* __restrict__ tok, float* __restrict__ att)
{
  __shared__ float e[WLEN];
  __shared__ float den_s;
  const int n = blockIdx.x, j = threadIdx.x;
  if (j < WLEN){
    float lgt = logits[n*WLEN + j];
    if (tok[n*WLEN + j] == 0) lgt -= 10000.0f;
    e[j] = lgt;
  }
  __syncthreads();
  if (j == 0){
    float mx = -1e30f;
    for (int ww = 0; ww < WLEN; ++ww) mx = fmaxf(mx, e[ww]);
    float den = 0.f;
    for (int ww = 0; ww < WLEN; ++ww){ float ee = expf(e[ww]-mx); e[ww] = ee; den += ee; }
    den_s = den;
  }
  __syncthreads();
  const float inv = 1.0f/den_s;
  float a = 0.f;
  for (int ww = 0; ww < WLEN; ++ww)
    a += e[ww]*bf2f(woutb[((size_t)n*WLEN + ww)*HIDN + j]);
  att[(size_t)n*HIDN + j] = a*inv;
}

// =======================================================================
// Fallback word LSTM (fp32, only if workspace too small for X)
// =======================================================================
__global__ __launch_bounds__(256) void word_gates_k(
    const int* __restrict__ tok, const float* __restrict__ emb,
    const float* __restrict__ Wih, const float* __restrict__ Whh,
    const float* __restrict__ bias, const float* __restrict__ hbuf,
    float* __restrict__ G, int t)
{
  __shared__ float As[32][68];
  __shared__ float Bs[32][68];
  const int tid = threadIdx.x;
  const int m0 = blockIdx.x*64, n0 = blockIdx.y*64;
  const int tx = tid & 15, ty = tid >> 4;
  const int lr = tid >> 3;
  const int lc = (tid & 7) * 4;
  float acc[4][4] = {};
  for (int kt = 0; kt < 16; ++kt){
    const int k0 = (kt & 7)*32;
    const bool xp = (kt < 8);
    #pragma unroll
    for (int hf = 0; hf < 2; ++hf){
      const int r = lr + hf*32;
      float4 av, bv;
      if (xp){
        const int token = tok[(m0+r)*WLEN + t];
        av = *reinterpret_cast<const float4*>(emb + (size_t)token*EMBD + k0 + lc);
      } else {
        av = *reinterpret_cast<const float4*>(hbuf + (size_t)(m0+r)*HIDN + k0 + lc);
      }
      const float* bptr = (xp ? Wih : Whh) + (size_t)(n0+r)*HIDN + k0 + lc;
      bv = *reinterpret_cast<const float4*>(bptr);
      As[lc+0][r]=av.x; As[lc+1][r]=av.y; As[lc+2][r]=av.z; As[lc+3][r]=av.w;
      Bs[lc+0][r]=bv.x; Bs[lc+1][r]=bv.y; Bs[lc+2][r]=bv.z; Bs[lc+3][r]=bv.w;
    }
    __syncthreads();
    #pragma unroll
    for (int kk = 0; kk < 32; ++kk){
      const float4 a = *reinterpret_cast<const float4*>(&As[kk][ty*4]);
      const float4 b = *reinterpret_cast<const float4*>(&Bs[kk][tx*4]);
      acc[0][0] += a.x*b.x; acc[0][1] += a.x*b.y; acc[0][2] += a.x*b.z; acc[0][3] += a.x*b.w;
      acc[1][0] += a.y*b.x; acc[1][1] += a.y*b.y; acc[1][2] += a.y*b.z; acc[1][3] += a.y*b.w;
      acc[2][0] += a.z*b.x; acc[2][1] += a.z*b.y; acc[2][2] += a.z*b.z; acc[2][3] += a.z*b.w;
      acc[3][0] += a.w*b.x; acc[3][1] += a.w*b.y; acc[3][2] += a.w*b.z; acc[3][3] += a.w*b.w;
    }
    __syncthreads();
  }
  const float4 bb = *reinterpret_cast<const float4*>(bias + n0 + tx*4);
  #pragma unroll
  for (int i = 0; i < 4; ++i){
    float4 o;
    o.x = acc[i][0]+bb.x; o.y = acc[i][1]+bb.y; o.z = acc[i][2]+bb.z; o.w = acc[i][3]+bb.w;
    *reinterpret_cast<float4*>(G + (size_t)(m0+ty*4+i)*GATES + n0 + tx*4) = o;
  }
}

__global__ __launch_bounds__(256) void word_update_k(
  const float* __restrict__ G, float* __restrict__ h, float* __restrict__ c,
  unsigned short* __restrict__ woutb, int t)
{
  int idx = blockIdx.x*256 + threadIdx.x;
  int m = idx >> 8, j = idx & 255;
  const float* g = G + (size_t)m*GATES;
  float gi = g[j], gf = g[HIDN+j], gg = g[2*HIDN+j], go = g[3*HIDN+j];
  float cc = c[idx];
  cc = sigf(gf)*cc + sigf(gi)*tanhf(gg);
  float hh = sigf(go)*tanhf(cc);
  c[idx] = cc; h[idx] = hh;
  woutb[(size_t)m*WLEN*HIDN + (size_t)t*HIDN + j] = f2bf(hh);
}

// =======================================================================
// conv+sess recurrent LSTM (round-3 proven): 512 thr, f16 weights
// =======================================================================
__global__ __launch_bounds__(512, 2) void recur512_k(
  const float* __restrict__ xwc, const f16* __restrict__ w16c, float* __restrict__ convb,
  const float* __restrict__ xws, const f16* __restrict__ w16s, float* __restrict__ soutb)
{
  const float* xw; const f16* w16; float* out; int seq, T;
  if (blockIdx.x < 8){ seq = blockIdx.x;     T = 128; xw = xwc; w16 = w16c; out = convb; }
  else               { seq = blockIdx.x - 8; T = 32;  xw = xws; w16 = w16s; out = soutb; }

  extern __shared__ char smem[];
  uint4* w_lds  = (uint4*)smem;
  float* g_s    = (float*)(smem + 131072);
  f16*   h_half = (f16*)(smem + 131072 + 4096);
  const uint4* h4 = (const uint4*)h_half;

  const int tid = threadIdx.x;
  const int n0 = tid, n1 = tid + 512;

  #pragma unroll
  for (int cth = 0; cth < 8; ++cth){
    w_lds[cth*1024 + n0] = *reinterpret_cast<const uint4*>(w16 + (size_t)n0*HIDN + 192 + cth*8);
    w_lds[cth*1024 + n1] = *reinterpret_cast<const uint4*>(w16 + (size_t)n1*HIDN + 192 + cth*8);
  }
  uint4 wr0[24], wr1[24];
  #pragma unroll
  for (int cth = 0; cth < 24; ++cth){
    wr0[cth] = *reinterpret_cast<const uint4*>(w16 + (size_t)n0*HIDN + cth*8);
    wr1[cth] = *reinterpret_cast<const uint4*>(w16 + (size_t)n1*HIDN + cth*8);
  }
  if (tid < 128) reinterpret_cast<uint4*>(h_half)[tid >> 2] = uint4{0,0,0,0};
  float c_reg = 0.f;
  __syncthreads();

  for (int t = 0; t < T; ++t){
    float acc0 = xw[(size_t)(seq*T + t)*GATES + n0];
    float acc1 = xw[(size_t)(seq*T + t)*GATES + n1];
    float a0=0.f, a1=0.f, a2=0.f, a3=0.f;
    #pragma unroll
    for (int k = 0; k < 24; k += 4){
      const uint4 h0 = h4[k+0], h1 = h4[k+1], h2 = h4[k+2], h3 = h4[k+3];
      a0 = dot8(wr0[k+0], h0, a0);
      a1 = dot8(wr0[k+1], h1, a1);
      a2 = dot8(wr0[k+2], h2, a2);
      a3 = dot8(wr0[k+3], h3, a3);
      acc1 = dot8(wr1[k+0], h0, acc1);
      acc1 = dot8(wr1[k+1], h1, acc1);
      acc1 = dot8(wr1[k+2], h2, acc1);
      acc1 = dot8(wr1[k+3], h3, acc1);
    }
    #pragma unroll
    for (int cth = 0; cth < 8; ++cth){
      const uint4 hv = h4[24 + cth];
      const uint4 w0 = w_lds[cth*1024 + n0];
      const uint4 w1 = w_lds[cth*1024 + n1];
      a0 = dot8(w0, hv, a0);
      acc1 = dot8(w1, hv, acc1);
    }
    g_s[n0] = acc0 + (a0+a1) + (a2+a3);
    g_s[n1] = acc1;
    __syncthreads();
    if (tid < HIDN){
      const int j = tid;
      float gi = g_s[j], gf = g_s[HIDN+j], gg = g_s[2*HIDN+j], go = g_s[3*HIDN+j];
      float cc = sigf(gf)*c_reg + sigf(gi)*tanhf(gg);
      c_reg = cc;
      float hh = sigf(go)*tanhf(cc);
      h_half[j] = (f16)hh;
      out[(size_t)(seq*T + t)*HIDN + j] = hh;
    }
    __syncthreads();
  }
}

// =======================================================================
// Parallel state "scan" prep
// =======================================================================
__global__ __launch_bounds__(256) void scan_prep_k(
  const float* __restrict__ sess_out, const float* __restrict__ conv_out,
  const int* __restrict__ stm, float* __restrict__ state, float* __restrict__ onec)
{
  const int bl = blockIdx.x;
  const int b = bl >> 7, l = bl & 127;
  const int j = threadIdx.x;
  float ones = 0.f;
  #pragma unroll
  for (int s = 1; s < SNUM; ++s){
    const int sv = stm[(size_t)bl*SNUM + s];
    float vg = 0.f;
    if (sv > 0){
      int p = sv - 1; if (p > PLEN-1) p = PLEN-1;
      vg = sess_out[((size_t)(b*4 + (s-1))*PLEN + p)*HIDN + j];
    }
    float v = vg;
    if (sv == -1){
      v = 0.f;
      if (l > 0){
        const int pv = stm[(size_t)(bl-1)*SNUM + s];
        if (pv > 0){
          int p2 = pv - 1; if (p2 > PLEN-1) p2 = PLEN-1;
          v = sess_out[((size_t)(b*4 + (s-1))*PLEN + p2)*HIDN + j];
        }
      }
    }
    if (sv != 0) ones += v;
    state[((size_t)bl*SNUM + s)*HIDN + j] = vg;
  }
  onec[(size_t)bl*(2*HIDN) + j] = ones * 0.25f;
  const int lp = (l == 0) ? 0 : (l-1);
  onec[(size_t)bl*(2*HIDN) + HIDN + j] = conv_out[((size_t)(b*LLEN + lp))*HIDN + j];
}

// =======================================================================
// final scores + log_softmax
// =======================================================================
__global__ __launch_bounds__(256) void scores_k(
  const float* __restrict__ state, const float* __restrict__ up, float* __restrict__ out)
{
  const int n = blockIdx.x, j = threadIdx.x;
  __shared__ float red[SNUM][4];
  const float u = up[(size_t)n*HIDN + j];
  const int lane = j & 63, wid = j >> 6;
  #pragma unroll
  for (int s = 0; s < SNUM; ++s){
    float p = state[((size_t)n*SNUM + s)*HIDN + j]*u;
    for (int off = 32; off; off >>= 1) p += __shfl_down(p, off, 64);
    if (lane == 0) red[s][wid] = p;
  }
  __syncthreads();
  if (j == 0){
    float sc[SNUM]; float mx = -1e30f;
    #pragma unroll
    for (int s = 0; s < SNUM; ++s){
      sc[s] = red[s][0]+red[s][1]+red[s][2]+red[s][3];
      mx = fmaxf(mx, sc[s]);
    }
    float den = 0.f;
    #pragma unroll
    for (int s = 0; s < SNUM; ++s) den += expf(sc[s]-mx);
    const float ls = logf(den);
    #pragma unroll
    for (int s = 0; s < SNUM; ++s) out[(size_t)n*SNUM + s] = sc[s]-mx-ls;
  }
}

// ---------------- workspace layout (float offsets) ----------------
static const size_t OFF_G     = 0;
static const size_t OFF_H     = OFF_G     + 1048576;
static const size_t OFF_C     = OFF_H     + 262144;
static const size_t OFF_ATT   = OFF_C     + 262144;
static const size_t OFF_XWC   = OFF_ATT   + 262144;
static const size_t OFF_XWS   = OFF_XWC   + 1048576;
static const size_t OFF_CONV  = OFF_XWS   + 1048576;
static const size_t OFF_SOUT  = OFF_CONV  + 262144;
static const size_t OFF_STATE = OFF_SOUT  + 262144;
static const size_t OFF_ONEC  = OFF_STATE + 1310720;
static const size_t OFF_UP    = OFF_ONEC  + 524288;
static const size_t OFF_LOG   = OFF_UP    + 262144;
static const size_t OFF_GIDX2 = OFF_LOG   + 49152;
static const size_t OFF_W16C  = OFF_GIDX2 + 49152;
static const size_t OFF_W16S  = OFF_W16C  + 131072;
static const size_t OFF_UWHHB = OFF_W16S  + 131072;
static const size_t OFF_WIHB  = OFF_UWHHB + 131072;
static const size_t OFF_WS1B  = OFF_WIHB  + 131072;
static const size_t OFF_WOUTB = OFF_WS1B  + 32768;
static const size_t OFF_X     = OFF_WOUTB + 6291456;
static const size_t NEED_X_FLOATS = OFF_X + (size_t)49152*1024;

static const size_t WORD_LDS_BYTES  = 131072 + 2*8192;
static const size_t RECUR_LDS_BYTES = 131072 + 4096 + 512;

extern "C" void kernel_launch(void* const* d_in, const int* in_sizes, int n_in,
                              void* d_out, int out_size, void* d_ws, size_t ws_size,
                              hipStream_t stream)
{
  const int*   tok   = (const int*)  d_in[0];
  const int*   perm  = (const int*)  d_in[2];
  const int*   stm   = (const int*)  d_in[3];
  const float* emb   = (const float*)d_in[5];
  const float* uWih  = (const float*)d_in[6];
  const float* uWhh  = (const float*)d_in[7];
  const float* ub    = (const float*)d_in[8];
  const float* ws1   = (const float*)d_in[9];
  const float* ws2   = (const float*)d_in[10];
  const float* cWih  = (const float*)d_in[11];
  const float* cWhh  = (const float*)d_in[12];
  const float* cb    = (const float*)d_in[13];
  const float* sWih  = (const float*)d_in[14];
  const float* sWhh  = (const float*)d_in[15];
  const float* sb    = (const float*)d_in[16];
  const float* Wp    = (const float*)d_in[17];
  const float* bp    = (const float*)d_in[18];
  const float* Ws    = (const float*)d_in[19];
  const float* bs    = (const float*)d_in[20];

  float* wsf    = (float*)d_ws;
  float* G      = wsf + OFF_G;
  float* h      = wsf + OFF_H;
  float* c      = wsf + OFF_C;
  float* att    = wsf + OFF_ATT;
  float* xwc    = wsf + OFF_XWC;
  float* xws    = wsf + OFF_XWS;
  float* convb  = wsf + OFF_CONV;
  float* soutb  = wsf + OFF_SOUT;
  float* statem = wsf + OFF_STATE;
  float* onec   = wsf + OFF_ONEC;
  float* upb    = wsf + OFF_UP;
  float* logits = wsf + OFF_LOG;
  int*   gidx2  = (int*)(wsf + OFF_GIDX2);
  f16*   w16c   = (f16*)(wsf + OFF_W16C);
  f16*   w16s   = (f16*)(wsf + OFF_W16S);
  unsigned short* uwhhb = (unsigned short*)(wsf + OFF_UWHHB);
  unsigned short* wihb  = (unsigned short*)(wsf + OFF_WIHB);
  unsigned short* ws1b  = (unsigned short*)(wsf + OFF_WS1B);
  unsigned short* woutb = (unsigned short*)(wsf + OFF_WOUTB);
  float* X      = wsf + OFF_X;

  const bool useX = ws_size >= NEED_X_FLOATS*sizeof(float);

  hipFuncSetAttribute(reinterpret_cast<const void*>(word_stream_k),
                      hipFuncAttributeMaxDynamicSharedMemorySize, (int)WORD_LDS_BYTES);
  hipFuncSetAttribute(reinterpret_cast<const void*>(recur512_k),
                      hipFuncAttributeMaxDynamicSharedMemorySize, (int)RECUR_LDS_BYTES);

  cvt_w16_k<<<1024, 256, 0, stream>>>(cWhh, sWhh, w16c, w16s);
  cvt_bf16_k<<<256, 256, 0, stream>>>(uWhh, uwhhb, 262144);
  cvt_bf16_k<<<256, 256, 0, stream>>>(uWih, wihb, 262144);
  cvt_bf16_k<<<64, 256, 0, stream>>>(ws1, ws1b, 65536);

  if (useX){
    remap_k<<<192, 256, 0, stream>>>(tok, gidx2);
    xgemm_k<<<dim3(768,16), 256, 0, stream>>>(emb, wihb, ub, gidx2, X);
    word_stream_k<<<64, 256, WORD_LDS_BYTES, stream>>>(X, uwhhb, woutb);
  } else {
    hipMemsetAsync(h, 0, 2*262144*sizeof(float), stream);
    for (int t = 0; t < WLEN; ++t){
      word_gates_k<<<dim3(16,16), 256, 0, stream>>>(tok, emb, uWih, uWhh, ub, h, G, t);
      word_update_k<<<1024, 256, 0, stream>>>(G, h, c, woutb, t);
    }
  }

  attlog_k<<<768, 256, 0, stream>>>(woutb, ws1b, ws2, logits);
  att_softmax_k<<<1024, 256, 0, stream>>>(woutb, logits, tok, att);

  gemm_abt64_k<false,true,false,false><<<dim3(16,16), 256, 0, stream>>>(
    att, nullptr, cWih, cb, xwc, nullptr, 256, GATES, GATES);
  gemm_abt64_k<true,true,false,false><<<dim3(16,16), 256, 0, stream>>>(
    att, nullptr, sWih, sb, xws, perm, 256, GATES, GATES);

  recur512_k<<<40, 512, RECUR_LDS_BYTES, stream>>>(xwc, w16c, convb, xws, w16s, soutb);

  scan_prep_k<<<1024, 256, 0, stream>>>(soutb, convb, stm, statem, onec);
  gemm_abt64_k<false,true,true,false><<<dim3(16,4), 256, 0, stream>>>(
    onec, nullptr, Wp, bp, statem, nullptr, 512, HIDN, SNUM*HIDN);

  gemm_abt64_k<false,true,true,true><<<dim3(16,4), 256, 0, stream>>>(
    att, convb, Ws, bs, upb, nullptr, 512, HIDN, HIDN);
  scores_k<<<1024, 256, 0, stream>>>(statem, upb, (float*)d_out);
}